// Round 5
// baseline (322.019 us; speedup 1.0000x reference)
//
#include <hip/hip_runtime.h>
#include <stdint.h>

// YatCausalAttention on MI355X (gfx950).
// Inputs FP32, output FP32. Intermediates FP16 via f16 MFMA, fp32 accum.
// Pipeline: cvt_x -> transpose+cvt weights -> gemm<128>(x,wqkvT) -> qkv(fp16)
//           -> yat flash attention (128-q blocks) -> gemm<64> -> out.
// ws (fp16 elems): wqkvT 3072*1024 | woT 1024*1024 | qkv 4096*3072 | xh/attn 4096*1024 = 40 MB
// R14: QBLK=128 — each block covers 128 q rows (wave = two 16-row halves,
// low/high). K/V staging (global loads, sumsq+shfl, V repack, addressing,
// barrier) paid once per 64-key tile now serves 2x the scores; K/V
// ds_read_b128 fragments shared by both halves (LDS reads per score halve).
// Block-iters 16.9K -> 8.7K. Low half diag at kt=NT-2; high-only epilogue
// pass at kt=NT-1. Q stages into Kp[1]/Vt[1] (iter-0 commit targets are
// Kp[0]/Vt[0], disjoint). Grid (32 bh, 16 y), y->q-block map interleaved so
// dispatch rounds have equal total tiles. Softmax/PV math per half unchanged
// from R13 (swapped QK^T, in-reg P via cvt_pkrtz+permlane, l via ones-MFMA,
// double-buffered K/V, 1 barrier/iter). GEMMs unchanged.

#define TSEQ 2048
#define BATCH 2

typedef _Float16 f16x8 __attribute__((ext_vector_type(8)));
typedef __fp16 fp16x2 __attribute__((ext_vector_type(2)));
typedef float f32x4 __attribute__((ext_vector_type(4)));
typedef unsigned int u32x2 __attribute__((ext_vector_type(2)));

#define MFMA16(a, b, c) __builtin_amdgcn_mfma_f32_16x16x32_f16(a, b, c, 0, 0, 0)

__device__ __forceinline__ unsigned short f2h(float f) {
  union { _Float16 h; unsigned short u; } v;
  v.h = (_Float16)f;
  return v.u;
}
__device__ __forceinline__ float h2f(unsigned short u) {
  union { unsigned short u; _Float16 h; } v;
  v.u = u;
  return (float)v.h;
}
__device__ __forceinline__ unsigned int pack2h(float lo, float hi) {
  return (unsigned int)f2h(lo) | ((unsigned int)f2h(hi) << 16);
}
__device__ __forceinline__ float sumsq_u32(unsigned int u) {
  float lo = h2f(u & 0xffffu);
  float hi = h2f(u >> 16);
  return lo * lo + hi * hi;
}
__device__ __forceinline__ void async_ld16(const void* g, const void* l) {
  __builtin_amdgcn_global_load_lds((const __attribute__((address_space(1))) void*)g,
                                   (__attribute__((address_space(3))) void*)l,
                                   16, 0, 0);
}
// pack two f32 -> one u32 of two f16 (v_cvt_pkrtz_f16_f32, single VALU op)
__device__ __forceinline__ unsigned int pk_f16(float lo, float hi) {
  union { fp16x2 h; unsigned int u; } c;
  c.h = __builtin_amdgcn_cvt_pkrtz(lo, hi);
  return c.u;
}

// ---------------- x: fp32 -> fp16, 8 elems/thread ----------------
__global__ __launch_bounds__(256) void cvt_x(const float* __restrict__ src,
                                             unsigned short* __restrict__ dst) {
  const int i = (blockIdx.x * 256 + threadIdx.x) * 8;
  const float4 a = *(const float4*)(src + i);
  const float4 b = *(const float4*)(src + i + 4);
  uint4 o;
  o.x = pack2h(a.x, a.y); o.y = pack2h(a.z, a.w);
  o.z = pack2h(b.x, b.y); o.w = pack2h(b.z, b.w);
  *(uint4*)(dst + i) = o;
}

// ------------- weight transpose+convert: src[K][N] (fp32) -> dst[N][K] (fp16) -------------
__global__ __launch_bounds__(256) void transpose_w(const float* __restrict__ src,
                                                   unsigned short* __restrict__ dst,
                                                   int K, int N) {
  __shared__ unsigned short tile[32][33];
  const int tx = threadIdx.x, ty = threadIdx.y;           // (32,8)
  const int nb = blockIdx.x * 32, kb = blockIdx.y * 32;
#pragma unroll
  for (int i = 0; i < 4; i++)
    tile[ty + 8 * i][tx] = f2h(src[(size_t)(kb + ty + 8 * i) * N + nb + tx]);
  __syncthreads();
#pragma unroll
  for (int i = 0; i < 4; i++)
    dst[(size_t)(nb + ty + 8 * i) * K + kb + tx] = tile[tx][ty + 8 * i];
}

// ------------- C[M][TN-tile] = A[M][K] * Bt[N][K]^T + bias[N]  (fp16 in, fp32 acc) -------------
// 128xTN tile, BK=32, global_load_lds width=16. TN=128: wave=64x64 (4x4 MFMA).
// TN=64: wave=64x32 (4x2 MFMA), grid doubles -> 2 blocks/CU for small-N gemm.
template <int TN, bool OUT_F32>
__global__ __launch_bounds__(256) void gemm_bt(const unsigned short* __restrict__ A,
                                               const unsigned short* __restrict__ Bt,
                                               const float* __restrict__ bias,
                                               void* __restrict__ Cp,
                                               int N, int K) {
  __shared__ __attribute__((aligned(16))) unsigned short Atile[128 * 32];
  __shared__ __attribute__((aligned(16))) unsigned short Btile[TN * 32];
  constexpr int NJ = TN / 32;  // 16-col tiles per wave
  const int tid = threadIdx.x;
  const int w = tid >> 6, lane = tid & 63;
  const int quad = lane >> 4, l15 = lane & 15;
  const int m0 = blockIdx.y * 128, n0 = blockIdx.x * TN;
  const int wr = w >> 1, wc = w & 1;
  const int nwc = wc * (TN / 2);
  f32x4 acc[4][NJ] = {};
  for (int kt = 0; kt < K; kt += 32) {
    __syncthreads();  // previous iteration's fragment reads complete
#pragma unroll
    for (int it = 0; it < 2; it++) {      // A: 128 rows
      const int c = it * 256 + tid;       // chunk: row = c>>2, 8-elem k-chunk = c&3
      async_ld16(A + (size_t)(m0 + (c >> 2)) * K + kt + (c & 3) * 8,
                 &Atile[(size_t)(it * 256 + w * 64) * 8]);   // wave-uniform LDS base
    }
#pragma unroll
    for (int it = 0; it < TN / 64; it++) {  // B: TN rows
      const int c = it * 256 + tid;
      async_ld16(Bt + (size_t)(n0 + (c >> 2)) * K + kt + (c & 3) * 8,
                 &Btile[(size_t)(it * 256 + w * 64) * 8]);
    }
    __syncthreads();  // vmcnt(0) drain lands the async copies
    f16x8 af[4], bfr[NJ];
#pragma unroll
    for (int i = 0; i < 4; i++)
      af[i] = *(const f16x8*)&Atile[(wr * 64 + i * 16 + l15) * 32 + quad * 8];
#pragma unroll
    for (int j = 0; j < NJ; j++)
      bfr[j] = *(const f16x8*)&Btile[(nwc + j * 16 + l15) * 32 + quad * 8];
#pragma unroll
    for (int i = 0; i < 4; i++)
#pragma unroll
      for (int j = 0; j < NJ; j++)
        acc[i][j] = MFMA16(af[i], bfr[j], acc[i][j]);
  }
  // epilogue: C/D layout col=lane&15, row=quad*4+reg
#pragma unroll
  for (int j = 0; j < NJ; j++) {
    const int n = n0 + nwc + j * 16 + l15;
    const float bv = bias[n];
#pragma unroll
    for (int i = 0; i < 4; i++) {
      const int mb = m0 + wr * 64 + i * 16 + quad * 4;
#pragma unroll
      for (int r = 0; r < 4; r++) {
        if constexpr (OUT_F32)
          ((float*)Cp)[(size_t)(mb + r) * N + n] = acc[i][j][r] + bv;
        else
          ((unsigned short*)Cp)[(size_t)(mb + r) * N + n] = f2h(acc[i][j][r] + bv);
      }
    }
  }
}

// ---------------- Yat causal flash attention (fp16 in/out, fp32 math) ----------------
// grid: (B*H, 16). Block 256 = 4 waves; wave w owns q rows {16w..16w+16} (low)
// and {64+16w..64+16w+16} (high) of a 128-row q block.
// score = dot^2 * rcp(qsq + ksq - 2 dot + 1e-6), causal, online softmax.
// S^T layout: accS = MFMA(K,Q) -> lane owns q = 16w+l15, t = nt*16+quad*4+r.
// P in registers: cvt_pkrtz -> permlane32/16_swap -> PV B-frags.
// Double-buffered Kp/Vt/ksq: 1 barrier/iter. K/V frag reads shared by halves.
__global__ __launch_bounds__(256, 4) void yat_attn(const unsigned short* __restrict__ qkv,
                                                   unsigned short* __restrict__ outp) {
  __shared__ __attribute__((aligned(16))) unsigned short Kp[2][64 * 72];  // [t][d]; Kp[1]=Qlo stage
  __shared__ __attribute__((aligned(16))) unsigned short Vt[2][64 * 72];  // [d][t]; Vt[1]=Qhi stage
  __shared__ float qsq[128], ksq[2][64];
  const int tid = threadIdx.x;
  const int w = tid >> 6, lane = tid & 63;
  const int quad = lane >> 4, l15 = lane & 15;
  const int bh = blockIdx.x, b = bh >> 4, h = bh & 15;
  // dispatch-round-balanced y -> q-block map: rounds {y<8} and {y>=8} have
  // equal total tile counts (interleaved map, sum 60 each).
  const int y = blockIdx.y, i7 = y & 7;
  const int yp = (y < 8) ? (15 - i7 - 2 * ((i7 + 1) >> 1)) : (14 - i7 - 2 * (i7 >> 1));
  const int NT = 2 * yp + 2;   // k-tiles for this q block
  const int q0 = yp * 128;     // first q row
  const unsigned short* base = qkv + (size_t)b * TSEQ * 3072 + h * 64;
  const int t = tid >> 2, dc = (tid & 3) * 16;   // K/Q staging: row t, 16 d's
  const int d0 = tid & 31, tg8 = tid >> 5;       // V staging: 2 d-rows, 8 t's

  // tile-0 K/V loads issued first (latency hides under Q staging)
  uint4 kreg0, kreg1;
  unsigned int vreg[8];
  {
    const unsigned short* gk = base + 1024 + (size_t)t * 3072 + dc;
    kreg0 = *(const uint4*)gk;
    kreg1 = *(const uint4*)(gk + 8);
    const unsigned short* gv = base + 2048 + (size_t)(tg8 * 8) * 3072 + 2 * d0;
#pragma unroll
    for (int s = 0; s < 8; s++)
      vreg[s] = *(const unsigned int*)(gv + (size_t)s * 3072);
  }
  {  // stage Q low half -> Kp[1], high half -> Vt[1], + row sums of squares
    const unsigned short* gL = base + (size_t)(q0 + t) * 3072 + dc;
    uint4 v0 = *(const uint4*)gL;
    uint4 v1 = *(const uint4*)(gL + 8);
    *(uint4*)&Kp[1][t * 72 + dc] = v0;
    *(uint4*)&Kp[1][t * 72 + dc + 8] = v1;
    float s = sumsq_u32(v0.x) + sumsq_u32(v0.y) + sumsq_u32(v0.z) + sumsq_u32(v0.w) +
              sumsq_u32(v1.x) + sumsq_u32(v1.y) + sumsq_u32(v1.z) + sumsq_u32(v1.w);
    s += __shfl_xor(s, 1);
    s += __shfl_xor(s, 2);
    if ((tid & 3) == 0) qsq[t] = s;
    const unsigned short* gH = base + (size_t)(q0 + 64 + t) * 3072 + dc;
    v0 = *(const uint4*)gH;
    v1 = *(const uint4*)(gH + 8);
    *(uint4*)&Vt[1][t * 72 + dc] = v0;
    *(uint4*)&Vt[1][t * 72 + dc + 8] = v1;
    s = sumsq_u32(v0.x) + sumsq_u32(v0.y) + sumsq_u32(v0.z) + sumsq_u32(v0.w) +
        sumsq_u32(v1.x) + sumsq_u32(v1.y) + sumsq_u32(v1.z) + sumsq_u32(v1.w);
    s += __shfl_xor(s, 1);
    s += __shfl_xor(s, 2);
    if ((tid & 3) == 0) qsq[64 + t] = s;
  }
  // commit K [t][d] + ksq + V^T [d][t] from regs into buffer `buf`
  auto commit = [&](int buf) {
    *(uint4*)&Kp[buf][t * 72 + dc] = kreg0;
    *(uint4*)&Kp[buf][t * 72 + dc + 8] = kreg1;
    float s = sumsq_u32(kreg0.x) + sumsq_u32(kreg0.y) + sumsq_u32(kreg0.z) +
              sumsq_u32(kreg0.w) + sumsq_u32(kreg1.x) + sumsq_u32(kreg1.y) +
              sumsq_u32(kreg1.z) + sumsq_u32(kreg1.w);
    s += __shfl_xor(s, 1);
    s += __shfl_xor(s, 2);
    if ((tid & 3) == 0) ksq[buf][t] = s;
    uint4 LO, HI;
    LO.x = (vreg[0] & 0xffffu) | (vreg[1] << 16);
    LO.y = (vreg[2] & 0xffffu) | (vreg[3] << 16);
    LO.z = (vreg[4] & 0xffffu) | (vreg[5] << 16);
    LO.w = (vreg[6] & 0xffffu) | (vreg[7] << 16);
    HI.x = (vreg[0] >> 16) | (vreg[1] & 0xffff0000u);
    HI.y = (vreg[2] >> 16) | (vreg[3] & 0xffff0000u);
    HI.z = (vreg[4] >> 16) | (vreg[5] & 0xffff0000u);
    HI.w = (vreg[6] >> 16) | (vreg[7] & 0xffff0000u);
    *(uint4*)&Vt[buf][(2 * d0) * 72 + tg8 * 8] = LO;
    *(uint4*)&Vt[buf][(2 * d0 + 1) * 72 + tg8 * 8] = HI;
  };
  commit(0);  // targets Kp[0]/Vt[0] — disjoint from Q staging buffers
  {  // prefetch tile 1 (NT >= 2 always)
    const unsigned short* gk = base + 1024 + (size_t)(64 + t) * 3072 + dc;
    kreg0 = *(const uint4*)gk;
    kreg1 = *(const uint4*)(gk + 8);
    const unsigned short* gv = base + 2048 + (size_t)(64 + tg8 * 8) * 3072 + 2 * d0;
#pragma unroll
    for (int s = 0; s < 8; s++)
      vreg[s] = *(const unsigned int*)(gv + (size_t)s * 3072);
  }
  __syncthreads();  // Q (Kp[1]/Vt[1]) + tile0 (Kp[0]/Vt[0]/ksq[0]) visible
  // hoisted loop-invariant Q fragments, low + high halves
  const f16x8 aq0L = *(const f16x8*)&Kp[1][(w * 16 + l15) * 72 + quad * 8];
  const f16x8 aq1L = *(const f16x8*)&Kp[1][(w * 16 + l15) * 72 + 32 + quad * 8];
  const f16x8 aq0H = *(const f16x8*)&Vt[1][(w * 16 + l15) * 72 + quad * 8];
  const f16x8 aq1H = *(const f16x8*)&Vt[1][(w * 16 + l15) * 72 + 32 + quad * 8];
  const f16x8 onesf = {(_Float16)1.f, (_Float16)1.f, (_Float16)1.f, (_Float16)1.f,
                       (_Float16)1.f, (_Float16)1.f, (_Float16)1.f, (_Float16)1.f};
  const int wl = w * 16 + l15;            // lane's q row within its half
  const float qeL = qsq[wl] + 1e-6f;
  const float qeH = qsq[64 + wl] + 1e-6f;
  __syncthreads();  // all Q-frag reads done before iter0 commits Kp[1]/Vt[1]

  f32x4 accOL[4] = {}, accOH[4] = {};    // O^T: lane q = l15, d = 16i+quad*4+r
  float mL = 0.f, mH = 0.f;              // scores >= 0 so 0 is a valid init max
  float lL = 0.f, lH = 0.f;

  // per-half softmax+pack: pv[4][4] -> bp0/bp1 B-frags + alpha (updates m_run)
  auto soft_pack = [&](float pv[4][4], float& m_run, float& alpha,
                       f16x8& bp0v, f16x8& bp1v) {
    float tm = fmaxf(fmaxf(fmaxf(pv[0][0], pv[0][1]), fmaxf(pv[0][2], pv[0][3])),
                     fmaxf(fmaxf(pv[1][0], pv[1][1]), fmaxf(pv[1][2], pv[1][3])));
    tm = fmaxf(tm, fmaxf(fmaxf(fmaxf(pv[2][0], pv[2][1]), fmaxf(pv[2][2], pv[2][3])),
                         fmaxf(fmaxf(pv[3][0], pv[3][1]), fmaxf(pv[3][2], pv[3][3]))));
    tm = fmaxf(tm, __shfl_xor(tm, 16));
    tm = fmaxf(tm, __shfl_xor(tm, 32));
    const float mn = fmaxf(m_run, tm);
    alpha = __expf(m_run - mn);
    m_run = mn;
    unsigned int pa[4], pb[4];
#pragma unroll
    for (int nt = 0; nt < 4; nt++) {
      pa[nt] = pk_f16(__expf(pv[nt][0] - mn), __expf(pv[nt][1] - mn));
      pb[nt] = pk_f16(__expf(pv[nt][2] - mn), __expf(pv[nt][3] - mn));
    }
    union { f16x8 v; unsigned int u[4]; } bp0, bp1;
    u32x2 s0 = __builtin_amdgcn_permlane32_swap(pa[0], pa[1], false, false);
    u32x2 s1 = __builtin_amdgcn_permlane16_swap(s0.x, s0.y, false, false);
    bp0.u[0] = s1.x; bp0.u[2] = s1.y;
    s0 = __builtin_amdgcn_permlane32_swap(pb[0], pb[1], false, false);
    s1 = __builtin_amdgcn_permlane16_swap(s0.x, s0.y, false, false);
    bp0.u[1] = s1.x; bp0.u[3] = s1.y;
    s0 = __builtin_amdgcn_permlane32_swap(pa[2], pa[3], false, false);
    s1 = __builtin_amdgcn_permlane16_swap(s0.x, s0.y, false, false);
    bp1.u[0] = s1.x; bp1.u[2] = s1.y;
    s0 = __builtin_amdgcn_permlane32_swap(pb[2], pb[3], false, false);
    s1 = __builtin_amdgcn_permlane16_swap(s0.x, s0.y, false, false);
    bp1.u[1] = s1.x; bp1.u[3] = s1.y;
    bp0v = bp0.v; bp1v = bp1.v;
  };

  for (int kt = 0; kt <= NT - 2; kt++) {
    const int cur = kt & 1;
    // S^T = K Q^T for both halves; K frags read once, used twice
    f32x4 aSL[4] = {}, aSH[4] = {};
#pragma unroll
    for (int nt = 0; nt < 4; nt++) {
      const f16x8 bk0 = *(const f16x8*)&Kp[cur][(nt * 16 + l15) * 72 + quad * 8];
      const f16x8 bk1 = *(const f16x8*)&Kp[cur][(nt * 16 + l15) * 72 + 32 + quad * 8];
      aSL[nt] = MFMA16(bk0, aq0L, aSL[nt]);
      aSL[nt] = MFMA16(bk1, aq1L, aSL[nt]);
      aSH[nt] = MFMA16(bk0, aq0H, aSH[nt]);
      aSH[nt] = MFMA16(bk1, aq1H, aSH[nt]);
    }
    float pvL[4][4], pvH[4][4];
#pragma unroll
    for (int nt = 0; nt < 4; nt++) {
      const f32x4 k4 = *(const f32x4*)&ksq[cur][nt * 16 + quad * 4];
#pragma unroll
      for (int r = 0; r < 4; r++) {
        float d = aSL[nt][r];
        float den = __builtin_fmaf(-2.f, d, k4[r] + qeL);
        pvL[nt][r] = d * d * __builtin_amdgcn_rcpf(den);
        d = aSH[nt][r];
        den = __builtin_fmaf(-2.f, d, k4[r] + qeH);
        pvH[nt][r] = d * d * __builtin_amdgcn_rcpf(den);
      }
    }
    if (kt == NT - 2) {  // low-half diagonal tile (high is strictly below diag)
#pragma unroll
      for (int nt = 0; nt < 4; nt++)
#pragma unroll
        for (int r = 0; r < 4; r++)
          if (nt * 16 + quad * 4 + r > wl) pvL[nt][r] = -1e30f;
    }
    float alphaL, alphaH;
    f16x8 bpL0, bpL1, bpH0, bpH1;
    soft_pack(pvL, mL, alphaL, bpL0, bpL1);
    soft_pack(pvH, mH, alphaH, bpH0, bpH1);
    // commit tile kt+1 (always exists: kt <= NT-2); prefetch tile kt+2
    commit(cur ^ 1);
    if (kt + 2 <= NT - 1) {
      const unsigned short* gk = base + 1024 + (size_t)((kt + 2) * 64 + t) * 3072 + dc;
      kreg0 = *(const uint4*)gk;
      kreg1 = *(const uint4*)(gk + 8);
      const unsigned short* gv =
          base + 2048 + (size_t)((kt + 2) * 64 + tg8 * 8) * 3072 + 2 * d0;
#pragma unroll
      for (int s = 0; s < 8; s++)
        vreg[s] = *(const unsigned int*)(gv + (size_t)s * 3072);
    }
    // rescale O^T, l-sums via ones-MFMA, PV with shared V frag reads
#pragma unroll
    for (int i = 0; i < 4; i++) {
      accOL[i][0] *= alphaL; accOL[i][1] *= alphaL;
      accOL[i][2] *= alphaL; accOL[i][3] *= alphaL;
      accOH[i][0] *= alphaH; accOH[i][1] *= alphaH;
      accOH[i][2] *= alphaH; accOH[i][3] *= alphaH;
    }
    f32x4 aLL = {}, aLH = {};
    aLL = MFMA16(onesf, bpL0, aLL);
    aLL = MFMA16(onesf, bpL1, aLL);
    aLH = MFMA16(onesf, bpH0, aLH);
    aLH = MFMA16(onesf, bpH1, aLH);
#pragma unroll
    for (int i = 0; i < 4; i++) {
      const f16x8 av0 = *(const f16x8*)&Vt[cur][(i * 16 + l15) * 72 + quad * 8];
      const f16x8 av1 = *(const f16x8*)&Vt[cur][(i * 16 + l15) * 72 + 32 + quad * 8];
      accOL[i] = MFMA16(av0, bpL0, accOL[i]);
      accOL[i] = MFMA16(av1, bpL1, accOL[i]);
      accOH[i] = MFMA16(av0, bpH0, accOH[i]);
      accOH[i] = MFMA16(av1, bpH1, accOH[i]);
    }
    lL = lL * alphaL + aLL[0];
    lH = lH * alphaH + aLH[0];
    __syncthreads();  // reads of cur done; writes of cur^1 done
  }
  {  // final tile: high half only, diagonal mask
    const int cur = (NT - 1) & 1;
    f32x4 aSH[4] = {};
#pragma unroll
    for (int nt = 0; nt < 4; nt++) {
      const f16x8 bk0 = *(const f16x8*)&Kp[cur][(nt * 16 + l15) * 72 + quad * 8];
      const f16x8 bk1 = *(const f16x8*)&Kp[cur][(nt * 16 + l15) * 72 + 32 + quad * 8];
      aSH[nt] = MFMA16(bk0, aq0H, aSH[nt]);
      aSH[nt] = MFMA16(bk1, aq1H, aSH[nt]);
    }
    float pvH[4][4];
#pragma unroll
    for (int nt = 0; nt < 4; nt++) {
      const f32x4 k4 = *(const f32x4*)&ksq[cur][nt * 16 + quad * 4];
#pragma unroll
      for (int r = 0; r < 4; r++) {
        const float d = aSH[nt][r];
        const float den = __builtin_fmaf(-2.f, d, k4[r] + qeH);
        float sc = d * d * __builtin_amdgcn_rcpf(den);
        if (nt * 16 + quad * 4 + r > wl) sc = -1e30f;
        pvH[nt][r] = sc;
      }
    }
    float alphaH;
    f16x8 bpH0, bpH1;
    soft_pack(pvH, mH, alphaH, bpH0, bpH1);
#pragma unroll
    for (int i = 0; i < 4; i++) {
      accOH[i][0] *= alphaH; accOH[i][1] *= alphaH;
      accOH[i][2] *= alphaH; accOH[i][3] *= alphaH;
    }
    f32x4 aLH = {};
    aLH = MFMA16(onesf, bpH0, aLH);
    aLH = MFMA16(onesf, bpH1, aLH);
#pragma unroll
    for (int i = 0; i < 4; i++) {
      const f16x8 av0 = *(const f16x8*)&Vt[cur][(i * 16 + l15) * 72 + quad * 8];
      const f16x8 av1 = *(const f16x8*)&Vt[cur][(i * 16 + l15) * 72 + 32 + quad * 8];
      accOH[i] = MFMA16(av0, bpH0, accOH[i]);
      accOH[i] = MFMA16(av1, bpH1, accOH[i]);
    }
    lH = lH * alphaH + aLH[0];
  }

  // finalize: divide by l, transpose both halves through Kp[0]/Kp[1], store
  __syncthreads();  // all waves' last Kp/Vt reads complete before reuse
  const float liL = 1.0f / lL, liH = 1.0f / lH;
#pragma unroll
  for (int i = 0; i < 4; i++)
#pragma unroll
    for (int r = 0; r < 4; r++) {
      Kp[0][(w * 16 + l15) * 72 + i * 16 + quad * 4 + r] = f2h(accOL[i][r] * liL);
      Kp[1][(w * 16 + l15) * 72 + i * 16 + quad * 4 + r] = f2h(accOH[i][r] * liH);
    }
  __syncthreads();
  {
    uint4 o0 = *(const uint4*)&Kp[0][t * 72 + dc];
    uint4 o1 = *(const uint4*)&Kp[0][t * 72 + dc + 8];
    unsigned short* g = outp + (size_t)(b * TSEQ + q0 + t) * 1024 + h * 64 + dc;
    *(uint4*)g = o0;
    *(uint4*)(g + 8) = o1;
    o0 = *(const uint4*)&Kp[1][t * 72 + dc];
    o1 = *(const uint4*)&Kp[1][t * 72 + dc + 8];
    g = outp + (size_t)(b * TSEQ + q0 + 64 + t) * 1024 + h * 64 + dc;
    *(uint4*)g = o0;
    *(uint4*)(g + 8) = o1;
  }
}

extern "C" void kernel_launch(void* const* d_in, const int* in_sizes, int n_in,
                              void* d_out, int out_size, void* d_ws, size_t ws_size,
                              hipStream_t stream) {
  (void)in_sizes; (void)n_in; (void)out_size; (void)ws_size;
  const float* x     = (const float*)d_in[0];  // [2,2048,1024] fp32
  const float* w_qkv = (const float*)d_in[1];  // [1024,3072]   fp32
  const float* b_qkv = (const float*)d_in[2];  // [3072]        fp32
  const float* w_out = (const float*)d_in[3];  // [1024,1024]   fp32
  const float* b_out = (const float*)d_in[4];  // [1024]        fp32
  float* out = (float*)d_out;                  // [2,2048,1024] fp32

  unsigned short* wqkvT  = (unsigned short*)d_ws;                    // [3072][1024] fp16
  unsigned short* woT    = wqkvT + (size_t)3072 * 1024;              // [1024][1024] fp16
  unsigned short* qkvws  = woT + (size_t)1024 * 1024;                // [4096][3072] fp16
  unsigned short* xh     = qkvws + (size_t)4096 * 3072;              // [4096][1024] fp16
  unsigned short* attnws = xh;  // alias: xh dead after gemm1, attnws born at yat_attn

  cvt_x<<<dim3(4096 * 1024 / (256 * 8)), 256, 0, stream>>>(x, xh);
  transpose_w<<<dim3(3072 / 32, 1024 / 32), dim3(32, 8), 0, stream>>>(w_qkv, wqkvT, 1024, 3072);
  transpose_w<<<dim3(1024 / 32, 1024 / 32), dim3(32, 8), 0, stream>>>(w_out, woT, 1024, 1024);
  gemm_bt<128, false><<<dim3(3072 / 128, 4096 / 128), 256, 0, stream>>>(xh, wqkvT, b_qkv, qkvws, 3072, 1024);
  yat_attn<<<dim3(BATCH * 16, 16), 256, 0, stream>>>(qkvws, attnws);
  gemm_bt<64, true><<<dim3(1024 / 64, 4096 / 128), 256, 0, stream>>>(attnws, woT, b_out, out, 1024, 1024);
}

// Round 6
// 229.546 us; speedup vs baseline: 1.4028x; 1.4028x over previous
//
#include <hip/hip_runtime.h>
#include <stdint.h>

// YatCausalAttention on MI355X (gfx950).
// Inputs FP32, output FP32. Intermediates FP16 via f16 MFMA, fp32 accum.
// Pipeline: cvt_x -> transpose+cvt weights -> gemm<128>(x,wqkvT) -> qkv(fp16)
//           -> yat flash attention (128-q blocks) -> gemm<64> -> out.
// ws (fp16 elems): wqkvT 3072*1024 | woT 1024*1024 | qkv 4096*3072 | xh/attn 4096*1024 = 40 MB
// R15 = R14 (QBLK=128 amortization) with the scratch-spill fixed:
// (a) __launch_bounds__(256,2) -> 256-VGPR cap (R14's (256,4) capped at 128
//     while QBLK=128 state needs ~150 -> everything spilled, WRITE_SIZE 140MB);
// (b) soft_pack is a __forceinline__ free function taking four f32x4 BY VALUE
//     (R14's lambda took float[4][4] -> array decayed to pointer -> scratch);
// (c) scores computed in place on the accS f32x4s (no pv arrays);
// (d) ksq quad hoisted once per tile, shared by both halves.
// Everything else as R14: two 64-row halves per block share K/V staging,
// sumsq, repack, barriers, and K/V ds_read fragments. GEMMs unchanged.

#define TSEQ 2048
#define BATCH 2

typedef _Float16 f16x8 __attribute__((ext_vector_type(8)));
typedef __fp16 fp16x2 __attribute__((ext_vector_type(2)));
typedef float f32x4 __attribute__((ext_vector_type(4)));
typedef unsigned int u32x2 __attribute__((ext_vector_type(2)));

#define MFMA16(a, b, c) __builtin_amdgcn_mfma_f32_16x16x32_f16(a, b, c, 0, 0, 0)

__device__ __forceinline__ unsigned short f2h(float f) {
  union { _Float16 h; unsigned short u; } v;
  v.h = (_Float16)f;
  return v.u;
}
__device__ __forceinline__ float h2f(unsigned short u) {
  union { unsigned short u; _Float16 h; } v;
  v.u = u;
  return (float)v.h;
}
__device__ __forceinline__ unsigned int pack2h(float lo, float hi) {
  return (unsigned int)f2h(lo) | ((unsigned int)f2h(hi) << 16);
}
__device__ __forceinline__ float sumsq_u32(unsigned int u) {
  float lo = h2f(u & 0xffffu);
  float hi = h2f(u >> 16);
  return lo * lo + hi * hi;
}
__device__ __forceinline__ void async_ld16(const void* g, const void* l) {
  __builtin_amdgcn_global_load_lds((const __attribute__((address_space(1))) void*)g,
                                   (__attribute__((address_space(3))) void*)l,
                                   16, 0, 0);
}
// pack two f32 -> one u32 of two f16 (v_cvt_pkrtz_f16_f32, single VALU op)
__device__ __forceinline__ unsigned int pk_f16(float lo, float hi) {
  union { fp16x2 h; unsigned int u; } c;
  c.h = __builtin_amdgcn_cvt_pkrtz(lo, hi);
  return c.u;
}

// online-softmax tile step for one 16x64 score slab held as 4x f32x4 (BY VALUE
// — no arrays/pointers, keeps everything in VGPRs). Returns alpha; updates
// m_run; emits the two PV B-fragments via permlane32/16 swaps.
__device__ __forceinline__ float soft_pack(f32x4 p0, f32x4 p1, f32x4 p2, f32x4 p3,
                                           float& m_run, f16x8& bp0v, f16x8& bp1v) {
  float tm = fmaxf(fmaxf(fmaxf(p0[0], p0[1]), fmaxf(p0[2], p0[3])),
                   fmaxf(fmaxf(p1[0], p1[1]), fmaxf(p1[2], p1[3])));
  tm = fmaxf(tm, fmaxf(fmaxf(fmaxf(p2[0], p2[1]), fmaxf(p2[2], p2[3])),
                       fmaxf(fmaxf(p3[0], p3[1]), fmaxf(p3[2], p3[3]))));
  tm = fmaxf(tm, __shfl_xor(tm, 16));
  tm = fmaxf(tm, __shfl_xor(tm, 32));
  const float mn = fmaxf(m_run, tm);
  const float alpha = __expf(m_run - mn);
  m_run = mn;
  const unsigned int pa0 = pk_f16(__expf(p0[0] - mn), __expf(p0[1] - mn));
  const unsigned int pb0 = pk_f16(__expf(p0[2] - mn), __expf(p0[3] - mn));
  const unsigned int pa1 = pk_f16(__expf(p1[0] - mn), __expf(p1[1] - mn));
  const unsigned int pb1 = pk_f16(__expf(p1[2] - mn), __expf(p1[3] - mn));
  const unsigned int pa2 = pk_f16(__expf(p2[0] - mn), __expf(p2[1] - mn));
  const unsigned int pb2 = pk_f16(__expf(p2[2] - mn), __expf(p2[3] - mn));
  const unsigned int pa3 = pk_f16(__expf(p3[0] - mn), __expf(p3[1] - mn));
  const unsigned int pb3 = pk_f16(__expf(p3[2] - mn), __expf(p3[3] - mn));
  union { f16x8 v; unsigned int u[4]; } bp0, bp1;
  u32x2 s0 = __builtin_amdgcn_permlane32_swap(pa0, pa1, false, false);
  u32x2 s1 = __builtin_amdgcn_permlane16_swap(s0.x, s0.y, false, false);
  bp0.u[0] = s1.x; bp0.u[2] = s1.y;
  s0 = __builtin_amdgcn_permlane32_swap(pb0, pb1, false, false);
  s1 = __builtin_amdgcn_permlane16_swap(s0.x, s0.y, false, false);
  bp0.u[1] = s1.x; bp0.u[3] = s1.y;
  s0 = __builtin_amdgcn_permlane32_swap(pa2, pa3, false, false);
  s1 = __builtin_amdgcn_permlane16_swap(s0.x, s0.y, false, false);
  bp1.u[0] = s1.x; bp1.u[2] = s1.y;
  s0 = __builtin_amdgcn_permlane32_swap(pb2, pb3, false, false);
  s1 = __builtin_amdgcn_permlane16_swap(s0.x, s0.y, false, false);
  bp1.u[1] = s1.x; bp1.u[3] = s1.y;
  bp0v = bp0.v;
  bp1v = bp1.v;
  return alpha;
}

// ---------------- x: fp32 -> fp16, 8 elems/thread ----------------
__global__ __launch_bounds__(256) void cvt_x(const float* __restrict__ src,
                                             unsigned short* __restrict__ dst) {
  const int i = (blockIdx.x * 256 + threadIdx.x) * 8;
  const float4 a = *(const float4*)(src + i);
  const float4 b = *(const float4*)(src + i + 4);
  uint4 o;
  o.x = pack2h(a.x, a.y); o.y = pack2h(a.z, a.w);
  o.z = pack2h(b.x, b.y); o.w = pack2h(b.z, b.w);
  *(uint4*)(dst + i) = o;
}

// ------------- weight transpose+convert: src[K][N] (fp32) -> dst[N][K] (fp16) -------------
__global__ __launch_bounds__(256) void transpose_w(const float* __restrict__ src,
                                                   unsigned short* __restrict__ dst,
                                                   int K, int N) {
  __shared__ unsigned short tile[32][33];
  const int tx = threadIdx.x, ty = threadIdx.y;           // (32,8)
  const int nb = blockIdx.x * 32, kb = blockIdx.y * 32;
#pragma unroll
  for (int i = 0; i < 4; i++)
    tile[ty + 8 * i][tx] = f2h(src[(size_t)(kb + ty + 8 * i) * N + nb + tx]);
  __syncthreads();
#pragma unroll
  for (int i = 0; i < 4; i++)
    dst[(size_t)(nb + ty + 8 * i) * K + kb + tx] = tile[tx][ty + 8 * i];
}

// ------------- C[M][TN-tile] = A[M][K] * Bt[N][K]^T + bias[N]  (fp16 in, fp32 acc) -------------
// 128xTN tile, BK=32, global_load_lds width=16. TN=128: wave=64x64 (4x4 MFMA).
// TN=64: wave=64x32 (4x2 MFMA), grid doubles -> 2 blocks/CU for small-N gemm.
template <int TN, bool OUT_F32>
__global__ __launch_bounds__(256) void gemm_bt(const unsigned short* __restrict__ A,
                                               const unsigned short* __restrict__ Bt,
                                               const float* __restrict__ bias,
                                               void* __restrict__ Cp,
                                               int N, int K) {
  __shared__ __attribute__((aligned(16))) unsigned short Atile[128 * 32];
  __shared__ __attribute__((aligned(16))) unsigned short Btile[TN * 32];
  constexpr int NJ = TN / 32;  // 16-col tiles per wave
  const int tid = threadIdx.x;
  const int w = tid >> 6, lane = tid & 63;
  const int quad = lane >> 4, l15 = lane & 15;
  const int m0 = blockIdx.y * 128, n0 = blockIdx.x * TN;
  const int wr = w >> 1, wc = w & 1;
  const int nwc = wc * (TN / 2);
  f32x4 acc[4][NJ] = {};
  for (int kt = 0; kt < K; kt += 32) {
    __syncthreads();  // previous iteration's fragment reads complete
#pragma unroll
    for (int it = 0; it < 2; it++) {      // A: 128 rows
      const int c = it * 256 + tid;       // chunk: row = c>>2, 8-elem k-chunk = c&3
      async_ld16(A + (size_t)(m0 + (c >> 2)) * K + kt + (c & 3) * 8,
                 &Atile[(size_t)(it * 256 + w * 64) * 8]);   // wave-uniform LDS base
    }
#pragma unroll
    for (int it = 0; it < TN / 64; it++) {  // B: TN rows
      const int c = it * 256 + tid;
      async_ld16(Bt + (size_t)(n0 + (c >> 2)) * K + kt + (c & 3) * 8,
                 &Btile[(size_t)(it * 256 + w * 64) * 8]);
    }
    __syncthreads();  // vmcnt(0) drain lands the async copies
    f16x8 af[4], bfr[NJ];
#pragma unroll
    for (int i = 0; i < 4; i++)
      af[i] = *(const f16x8*)&Atile[(wr * 64 + i * 16 + l15) * 32 + quad * 8];
#pragma unroll
    for (int j = 0; j < NJ; j++)
      bfr[j] = *(const f16x8*)&Btile[(nwc + j * 16 + l15) * 32 + quad * 8];
#pragma unroll
    for (int i = 0; i < 4; i++)
#pragma unroll
      for (int j = 0; j < NJ; j++)
        acc[i][j] = MFMA16(af[i], bfr[j], acc[i][j]);
  }
  // epilogue: C/D layout col=lane&15, row=quad*4+reg
#pragma unroll
  for (int j = 0; j < NJ; j++) {
    const int n = n0 + nwc + j * 16 + l15;
    const float bv = bias[n];
#pragma unroll
    for (int i = 0; i < 4; i++) {
      const int mb = m0 + wr * 64 + i * 16 + quad * 4;
#pragma unroll
      for (int r = 0; r < 4; r++) {
        if constexpr (OUT_F32)
          ((float*)Cp)[(size_t)(mb + r) * N + n] = acc[i][j][r] + bv;
        else
          ((unsigned short*)Cp)[(size_t)(mb + r) * N + n] = f2h(acc[i][j][r] + bv);
      }
    }
  }
}

// ---------------- Yat causal flash attention (fp16 in/out, fp32 math) ----------------
// grid: (B*H, 16). Block 256 = 4 waves; wave w owns q rows {16w..16w+16} (low)
// and {64+16w..64+16w+16} (high) of a 128-row q block.
// score = dot^2 * rcp(qsq + ksq - 2 dot + 1e-6), causal, online softmax.
// S^T layout: accS = MFMA(K,Q) -> lane owns q = 16w+l15, t = nt*16+quad*4+r.
// P in registers: cvt_pkrtz -> permlane32/16_swap -> PV B-frags.
// Double-buffered Kp/Vt/ksq: 1 barrier/iter. K/V frag reads shared by halves.
__global__ __launch_bounds__(256, 2) void yat_attn(const unsigned short* __restrict__ qkv,
                                                   unsigned short* __restrict__ outp) {
  __shared__ __attribute__((aligned(16))) unsigned short Kp[2][64 * 72];  // [t][d]; Kp[1]=Qlo stage
  __shared__ __attribute__((aligned(16))) unsigned short Vt[2][64 * 72];  // [d][t]; Vt[1]=Qhi stage
  __shared__ float qsq[128], ksq[2][64];
  const int tid = threadIdx.x;
  const int w = tid >> 6, lane = tid & 63;
  const int quad = lane >> 4, l15 = lane & 15;
  const int bh = blockIdx.x, b = bh >> 4, h = bh & 15;
  // dispatch-round-balanced y -> q-block map: rounds {y<8} and {y>=8} have
  // equal total tile counts (interleaved map, sum 60 each).
  const int y = blockIdx.y, i7 = y & 7;
  const int yp = (y < 8) ? (15 - i7 - 2 * ((i7 + 1) >> 1)) : (14 - i7 - 2 * (i7 >> 1));
  const int NT = 2 * yp + 2;   // k-tiles for this q block
  const int q0 = yp * 128;     // first q row
  const unsigned short* base = qkv + (size_t)b * TSEQ * 3072 + h * 64;
  const int t = tid >> 2, dc = (tid & 3) * 16;   // K/Q staging: row t, 16 d's
  const int d0 = tid & 31, tg8 = tid >> 5;       // V staging: 2 d-rows, 8 t's

  // tile-0 K/V loads issued first (latency hides under Q staging)
  uint4 kreg0, kreg1;
  unsigned int vreg[8];
  {
    const unsigned short* gk = base + 1024 + (size_t)t * 3072 + dc;
    kreg0 = *(const uint4*)gk;
    kreg1 = *(const uint4*)(gk + 8);
    const unsigned short* gv = base + 2048 + (size_t)(tg8 * 8) * 3072 + 2 * d0;
#pragma unroll
    for (int s = 0; s < 8; s++)
      vreg[s] = *(const unsigned int*)(gv + (size_t)s * 3072);
  }
  {  // stage Q low half -> Kp[1], high half -> Vt[1], + row sums of squares
    const unsigned short* gL = base + (size_t)(q0 + t) * 3072 + dc;
    uint4 v0 = *(const uint4*)gL;
    uint4 v1 = *(const uint4*)(gL + 8);
    *(uint4*)&Kp[1][t * 72 + dc] = v0;
    *(uint4*)&Kp[1][t * 72 + dc + 8] = v1;
    float s = sumsq_u32(v0.x) + sumsq_u32(v0.y) + sumsq_u32(v0.z) + sumsq_u32(v0.w) +
              sumsq_u32(v1.x) + sumsq_u32(v1.y) + sumsq_u32(v1.z) + sumsq_u32(v1.w);
    s += __shfl_xor(s, 1);
    s += __shfl_xor(s, 2);
    if ((tid & 3) == 0) qsq[t] = s;
    const unsigned short* gH = base + (size_t)(q0 + 64 + t) * 3072 + dc;
    v0 = *(const uint4*)gH;
    v1 = *(const uint4*)(gH + 8);
    *(uint4*)&Vt[1][t * 72 + dc] = v0;
    *(uint4*)&Vt[1][t * 72 + dc + 8] = v1;
    s = sumsq_u32(v0.x) + sumsq_u32(v0.y) + sumsq_u32(v0.z) + sumsq_u32(v0.w) +
        sumsq_u32(v1.x) + sumsq_u32(v1.y) + sumsq_u32(v1.z) + sumsq_u32(v1.w);
    s += __shfl_xor(s, 1);
    s += __shfl_xor(s, 2);
    if ((tid & 3) == 0) qsq[64 + t] = s;
  }
  // commit K [t][d] + ksq + V^T [d][t] from regs into buffer `buf`
  auto commit = [&](int buf) {
    *(uint4*)&Kp[buf][t * 72 + dc] = kreg0;
    *(uint4*)&Kp[buf][t * 72 + dc + 8] = kreg1;
    float s = sumsq_u32(kreg0.x) + sumsq_u32(kreg0.y) + sumsq_u32(kreg0.z) +
              sumsq_u32(kreg0.w) + sumsq_u32(kreg1.x) + sumsq_u32(kreg1.y) +
              sumsq_u32(kreg1.z) + sumsq_u32(kreg1.w);
    s += __shfl_xor(s, 1);
    s += __shfl_xor(s, 2);
    if ((tid & 3) == 0) ksq[buf][t] = s;
    uint4 LO, HI;
    LO.x = (vreg[0] & 0xffffu) | (vreg[1] << 16);
    LO.y = (vreg[2] & 0xffffu) | (vreg[3] << 16);
    LO.z = (vreg[4] & 0xffffu) | (vreg[5] << 16);
    LO.w = (vreg[6] & 0xffffu) | (vreg[7] << 16);
    HI.x = (vreg[0] >> 16) | (vreg[1] & 0xffff0000u);
    HI.y = (vreg[2] >> 16) | (vreg[3] & 0xffff0000u);
    HI.z = (vreg[4] >> 16) | (vreg[5] & 0xffff0000u);
    HI.w = (vreg[6] >> 16) | (vreg[7] & 0xffff0000u);
    *(uint4*)&Vt[buf][(2 * d0) * 72 + tg8 * 8] = LO;
    *(uint4*)&Vt[buf][(2 * d0 + 1) * 72 + tg8 * 8] = HI;
  };
  commit(0);  // targets Kp[0]/Vt[0] — disjoint from Q staging buffers
  {  // prefetch tile 1 (NT >= 2 always)
    const unsigned short* gk = base + 1024 + (size_t)(64 + t) * 3072 + dc;
    kreg0 = *(const uint4*)gk;
    kreg1 = *(const uint4*)(gk + 8);
    const unsigned short* gv = base + 2048 + (size_t)(64 + tg8 * 8) * 3072 + 2 * d0;
#pragma unroll
    for (int s = 0; s < 8; s++)
      vreg[s] = *(const unsigned int*)(gv + (size_t)s * 3072);
  }
  __syncthreads();  // Q (Kp[1]/Vt[1]) + tile0 (Kp[0]/Vt[0]/ksq[0]) visible
  // hoisted loop-invariant Q fragments, low + high halves
  const f16x8 aq0L = *(const f16x8*)&Kp[1][(w * 16 + l15) * 72 + quad * 8];
  const f16x8 aq1L = *(const f16x8*)&Kp[1][(w * 16 + l15) * 72 + 32 + quad * 8];
  const f16x8 aq0H = *(const f16x8*)&Vt[1][(w * 16 + l15) * 72 + quad * 8];
  const f16x8 aq1H = *(const f16x8*)&Vt[1][(w * 16 + l15) * 72 + 32 + quad * 8];
  const f16x8 onesf = {(_Float16)1.f, (_Float16)1.f, (_Float16)1.f, (_Float16)1.f,
                       (_Float16)1.f, (_Float16)1.f, (_Float16)1.f, (_Float16)1.f};
  const int wl = w * 16 + l15;            // lane's q row within its half
  const float qeL = qsq[wl] + 1e-6f;
  const float qeH = qsq[64 + wl] + 1e-6f;
  __syncthreads();  // all Q-frag reads done before iter0 commits Kp[1]/Vt[1]

  f32x4 accOL[4] = {}, accOH[4] = {};    // O^T: lane q = l15, d = 16i+quad*4+r
  float mL = 0.f, mH = 0.f;              // scores >= 0 so 0 is a valid init max
  float lL = 0.f, lH = 0.f;

  for (int kt = 0; kt <= NT - 2; kt++) {
    const int cur = kt & 1;
    // S^T = K Q^T for both halves; K frags read once, used twice
    f32x4 aSL[4] = {}, aSH[4] = {};
#pragma unroll
    for (int nt = 0; nt < 4; nt++) {
      const f16x8 bk0 = *(const f16x8*)&Kp[cur][(nt * 16 + l15) * 72 + quad * 8];
      const f16x8 bk1 = *(const f16x8*)&Kp[cur][(nt * 16 + l15) * 72 + 32 + quad * 8];
      aSL[nt] = MFMA16(bk0, aq0L, aSL[nt]);
      aSL[nt] = MFMA16(bk1, aq1L, aSL[nt]);
      aSH[nt] = MFMA16(bk0, aq0H, aSH[nt]);
      aSH[nt] = MFMA16(bk1, aq1H, aSH[nt]);
    }
    // ksq quad for this tile, shared by both halves
    f32x4 kq[4];
#pragma unroll
    for (int nt = 0; nt < 4; nt++)
      kq[nt] = *(const f32x4*)&ksq[cur][nt * 16 + quad * 4];
    // scores in place: lane q = wl(+64 for high), t = nt*16 + quad*4 + r
#pragma unroll
    for (int nt = 0; nt < 4; nt++) {
#pragma unroll
      for (int r = 0; r < 4; r++) {
        float d = aSL[nt][r];
        float den = __builtin_fmaf(-2.f, d, kq[nt][r] + qeL);
        aSL[nt][r] = d * d * __builtin_amdgcn_rcpf(den);
        d = aSH[nt][r];
        den = __builtin_fmaf(-2.f, d, kq[nt][r] + qeH);
        aSH[nt][r] = d * d * __builtin_amdgcn_rcpf(den);
      }
    }
    if (kt == NT - 2) {  // low-half diagonal tile (high is strictly below diag)
#pragma unroll
      for (int nt = 0; nt < 4; nt++)
#pragma unroll
        for (int r = 0; r < 4; r++)
          if (nt * 16 + quad * 4 + r > wl) aSL[nt][r] = -1e30f;
    }
    f16x8 bpL0, bpL1, bpH0, bpH1;
    const float alphaL = soft_pack(aSL[0], aSL[1], aSL[2], aSL[3], mL, bpL0, bpL1);
    const float alphaH = soft_pack(aSH[0], aSH[1], aSH[2], aSH[3], mH, bpH0, bpH1);
    // commit tile kt+1 (always exists: kt <= NT-2); prefetch tile kt+2
    commit(cur ^ 1);
    if (kt + 2 <= NT - 1) {
      const unsigned short* gk = base + 1024 + (size_t)((kt + 2) * 64 + t) * 3072 + dc;
      kreg0 = *(const uint4*)gk;
      kreg1 = *(const uint4*)(gk + 8);
      const unsigned short* gv =
          base + 2048 + (size_t)((kt + 2) * 64 + tg8 * 8) * 3072 + 2 * d0;
#pragma unroll
      for (int s = 0; s < 8; s++)
        vreg[s] = *(const unsigned int*)(gv + (size_t)s * 3072);
    }
    // rescale O^T, l-sums via ones-MFMA, PV with shared V frag reads
#pragma unroll
    for (int i = 0; i < 4; i++) {
      accOL[i][0] *= alphaL; accOL[i][1] *= alphaL;
      accOL[i][2] *= alphaL; accOL[i][3] *= alphaL;
      accOH[i][0] *= alphaH; accOH[i][1] *= alphaH;
      accOH[i][2] *= alphaH; accOH[i][3] *= alphaH;
    }
    f32x4 aLL = {}, aLH = {};
    aLL = MFMA16(onesf, bpL0, aLL);
    aLL = MFMA16(onesf, bpL1, aLL);
    aLH = MFMA16(onesf, bpH0, aLH);
    aLH = MFMA16(onesf, bpH1, aLH);
#pragma unroll
    for (int i = 0; i < 4; i++) {
      const f16x8 av0 = *(const f16x8*)&Vt[cur][(i * 16 + l15) * 72 + quad * 8];
      const f16x8 av1 = *(const f16x8*)&Vt[cur][(i * 16 + l15) * 72 + 32 + quad * 8];
      accOL[i] = MFMA16(av0, bpL0, accOL[i]);
      accOL[i] = MFMA16(av1, bpL1, accOL[i]);
      accOH[i] = MFMA16(av0, bpH0, accOH[i]);
      accOH[i] = MFMA16(av1, bpH1, accOH[i]);
    }
    lL = lL * alphaL + aLL[0];
    lH = lH * alphaH + aLH[0];
    __syncthreads();  // reads of cur done; writes of cur^1 done
  }
  {  // final tile: high half only, diagonal mask
    const int cur = (NT - 1) & 1;
    f32x4 aSH[4] = {};
#pragma unroll
    for (int nt = 0; nt < 4; nt++) {
      const f16x8 bk0 = *(const f16x8*)&Kp[cur][(nt * 16 + l15) * 72 + quad * 8];
      const f16x8 bk1 = *(const f16x8*)&Kp[cur][(nt * 16 + l15) * 72 + 32 + quad * 8];
      aSH[nt] = MFMA16(bk0, aq0H, aSH[nt]);
      aSH[nt] = MFMA16(bk1, aq1H, aSH[nt]);
    }
#pragma unroll
    for (int nt = 0; nt < 4; nt++) {
      const f32x4 k4 = *(const f32x4*)&ksq[cur][nt * 16 + quad * 4];
#pragma unroll
      for (int r = 0; r < 4; r++) {
        const float d = aSH[nt][r];
        const float den = __builtin_fmaf(-2.f, d, k4[r] + qeH);
        float sc = d * d * __builtin_amdgcn_rcpf(den);
        if (nt * 16 + quad * 4 + r > wl) sc = -1e30f;
        aSH[nt][r] = sc;
      }
    }
    f16x8 bpH0, bpH1;
    const float alphaH = soft_pack(aSH[0], aSH[1], aSH[2], aSH[3], mH, bpH0, bpH1);
#pragma unroll
    for (int i = 0; i < 4; i++) {
      accOH[i][0] *= alphaH; accOH[i][1] *= alphaH;
      accOH[i][2] *= alphaH; accOH[i][3] *= alphaH;
    }
    f32x4 aLH = {};
    aLH = MFMA16(onesf, bpH0, aLH);
    aLH = MFMA16(onesf, bpH1, aLH);
#pragma unroll
    for (int i = 0; i < 4; i++) {
      const f16x8 av0 = *(const f16x8*)&Vt[cur][(i * 16 + l15) * 72 + quad * 8];
      const f16x8 av1 = *(const f16x8*)&Vt[cur][(i * 16 + l15) * 72 + 32 + quad * 8];
      accOH[i] = MFMA16(av0, bpH0, accOH[i]);
      accOH[i] = MFMA16(av1, bpH1, accOH[i]);
    }
    lH = lH * alphaH + aLH[0];
  }

  // finalize: divide by l, transpose both halves through Kp[0]/Kp[1], store
  __syncthreads();  // all waves' last Kp/Vt reads complete before reuse
  const float liL = 1.0f / lL, liH = 1.0f / lH;
#pragma unroll
  for (int i = 0; i < 4; i++)
#pragma unroll
    for (int r = 0; r < 4; r++) {
      Kp[0][(w * 16 + l15) * 72 + i * 16 + quad * 4 + r] = f2h(accOL[i][r] * liL);
      Kp[1][(w * 16 + l15) * 72 + i * 16 + quad * 4 + r] = f2h(accOH[i][r] * liH);
    }
  __syncthreads();
  {
    uint4 o0 = *(const uint4*)&Kp[0][t * 72 + dc];
    uint4 o1 = *(const uint4*)&Kp[0][t * 72 + dc + 8];
    unsigned short* g = outp + (size_t)(b * TSEQ + q0 + t) * 1024 + h * 64 + dc;
    *(uint4*)g = o0;
    *(uint4*)(g + 8) = o1;
    o0 = *(const uint4*)&Kp[1][t * 72 + dc];
    o1 = *(const uint4*)&Kp[1][t * 72 + dc + 8];
    g = outp + (size_t)(b * TSEQ + q0 + 64 + t) * 1024 + h * 64 + dc;
    *(uint4*)g = o0;
    *(uint4*)(g + 8) = o1;
  }
}

extern "C" void kernel_launch(void* const* d_in, const int* in_sizes, int n_in,
                              void* d_out, int out_size, void* d_ws, size_t ws_size,
                              hipStream_t stream) {
  (void)in_sizes; (void)n_in; (void)out_size; (void)ws_size;
  const float* x     = (const float*)d_in[0];  // [2,2048,1024] fp32
  const float* w_qkv = (const float*)d_in[1];  // [1024,3072]   fp32
  const float* b_qkv = (const float*)d_in[2];  // [3072]        fp32
  const float* w_out = (const float*)d_in[3];  // [1024,1024]   fp32
  const float* b_out = (const float*)d_in[4];  // [1024]        fp32
  float* out = (float*)d_out;                  // [2,2048,1024] fp32

  unsigned short* wqkvT  = (unsigned short*)d_ws;                    // [3072][1024] fp16
  unsigned short* woT    = wqkvT + (size_t)3072 * 1024;              // [1024][1024] fp16
  unsigned short* qkvws  = woT + (size_t)1024 * 1024;                // [4096][3072] fp16
  unsigned short* xh     = qkvws + (size_t)4096 * 3072;              // [4096][1024] fp16
  unsigned short* attnws = xh;  // alias: xh dead after gemm1, attnws born at yat_attn

  cvt_x<<<dim3(4096 * 1024 / (256 * 8)), 256, 0, stream>>>(x, xh);
  transpose_w<<<dim3(3072 / 32, 1024 / 32), dim3(32, 8), 0, stream>>>(w_qkv, wqkvT, 1024, 3072);
  transpose_w<<<dim3(1024 / 32, 1024 / 32), dim3(32, 8), 0, stream>>>(w_out, woT, 1024, 1024);
  gemm_bt<128, false><<<dim3(3072 / 128, 4096 / 128), 256, 0, stream>>>(xh, wqkvT, b_qkv, qkvws, 3072, 1024);
  yat_attn<<<dim3(BATCH * 16, 16), 256, 0, stream>>>(qkvws, attnws);
  gemm_bt<64, true><<<dim3(1024 / 64, 4096 / 128), 256, 0, stream>>>(attnws, woT, b_out, out, 1024, 1024);
}

// Round 7
// 189.809 us; speedup vs baseline: 1.6965x; 1.2094x over previous
//
#include <hip/hip_runtime.h>
#include <stdint.h>

// YatCausalAttention on MI355X (gfx950).
// Inputs FP32, output FP32. Intermediates FP16 via f16 MFMA, fp32 accum.
// Pipeline: prep (cvt_x + both weight transposes, merged) -> gemm<128>
//           -> yat flash attention (64-q blocks, R13 structure) -> gemm<64>.
// ws (fp16 elems): wqkvT 3072*1024 | woT 1024*1024 | qkv 4096*3072 | xh/attn 4096*1024 = 40 MB
// R16 = R13 attention (QBLK=64, double-buffered K/V, 1 barrier/iter — the
// QBLK=128 experiments R14/R15 lost to spill resp. occupancy collapse) plus:
// (a) sumsq via v_dot2_f32_f16 (__builtin_amdgcn_fdot2): 1 op per packed
//     f16-pair instead of ~6 (extract+cvt+fma) — ~40 VALU/iter off commit;
// (b) V^T repack via v_perm_b32: 8 perms replace 24 and/or/shift;
// (c) cvt_x + transpose_w(wqkv) + transpose_w(wout) merged into ONE prep
//     kernel (block-range partition) — 6 launches -> 4.
// GEMMs unchanged.

#define TSEQ 2048
#define BATCH 2

typedef _Float16 f16x8 __attribute__((ext_vector_type(8)));
typedef _Float16 f16x2h __attribute__((ext_vector_type(2)));
typedef __fp16 fp16x2 __attribute__((ext_vector_type(2)));
typedef float f32x4 __attribute__((ext_vector_type(4)));
typedef unsigned int u32x2 __attribute__((ext_vector_type(2)));

#define MFMA16(a, b, c) __builtin_amdgcn_mfma_f32_16x16x32_f16(a, b, c, 0, 0, 0)

__device__ __forceinline__ unsigned short f2h(float f) {
  union { _Float16 h; unsigned short u; } v;
  v.h = (_Float16)f;
  return v.u;
}
__device__ __forceinline__ unsigned int pack2h(float lo, float hi) {
  return (unsigned int)f2h(lo) | ((unsigned int)f2h(hi) << 16);
}
// f32 acc += lo^2 + hi^2 of a packed f16 pair — single v_dot2_f32_f16
__device__ __forceinline__ float dot2acc(unsigned int u, float acc) {
  union { unsigned int u; f16x2h h; } c;
  c.u = u;
  return __builtin_amdgcn_fdot2(c.h, c.h, acc, false);
}
__device__ __forceinline__ void async_ld16(const void* g, const void* l) {
  __builtin_amdgcn_global_load_lds((const __attribute__((address_space(1))) void*)g,
                                   (__attribute__((address_space(3))) void*)l,
                                   16, 0, 0);
}
// pack two f32 -> one u32 of two f16 (v_cvt_pkrtz_f16_f32, single VALU op)
__device__ __forceinline__ unsigned int pk_f16(float lo, float hi) {
  union { fp16x2 h; unsigned int u; } c;
  c.h = __builtin_amdgcn_cvt_pkrtz(lo, hi);
  return c.u;
}

// ---------------- merged prep: cvt_x | transpose(w_qkv) | transpose(w_out) ----------------
// blocks [0,2048): x fp32->fp16, 8 elems/thread.
// blocks [2048,5120): w_qkv [1024][3072] -> wqkvT [3072][1024] fp16.
// blocks [5120,6144): w_out [1024][1024] -> woT   [1024][1024] fp16.
__global__ __launch_bounds__(256) void prep(const float* __restrict__ x,
                                            unsigned short* __restrict__ xh,
                                            const float* __restrict__ w_qkv,
                                            unsigned short* __restrict__ wqkvT,
                                            const float* __restrict__ w_out,
                                            unsigned short* __restrict__ woT) {
  __shared__ unsigned short tile[32][33];
  const int bid = blockIdx.x, tid = threadIdx.x;
  if (bid < 2048) {
    const int i = (bid * 256 + tid) * 8;
    const float4 a = *(const float4*)(x + i);
    const float4 b = *(const float4*)(x + i + 4);
    uint4 o;
    o.x = pack2h(a.x, a.y); o.y = pack2h(a.z, a.w);
    o.z = pack2h(b.x, b.y); o.w = pack2h(b.z, b.w);
    *(uint4*)(xh + i) = o;
    return;
  }
  const bool qkv = bid < 5120;
  const int b2 = qkv ? bid - 2048 : bid - 5120;
  const int NB = qkv ? 96 : 32;            // N/32
  const int N = NB * 32, K = 1024;
  const float* src = qkv ? w_qkv : w_out;
  unsigned short* dst = qkv ? wqkvT : woT;
  const int nb = (b2 % NB) * 32, kb = (b2 / NB) * 32;
  const int tx = tid & 31, ty = tid >> 5;  // (32,8)
#pragma unroll
  for (int i = 0; i < 4; i++)
    tile[ty + 8 * i][tx] = f2h(src[(size_t)(kb + ty + 8 * i) * N + nb + tx]);
  __syncthreads();
#pragma unroll
  for (int i = 0; i < 4; i++)
    dst[(size_t)(nb + ty + 8 * i) * K + kb + tx] = tile[tx][ty + 8 * i];
}

// ------------- C[M][TN-tile] = A[M][K] * Bt[N][K]^T + bias[N]  (fp16 in, fp32 acc) -------------
// 128xTN tile, BK=32, global_load_lds width=16. TN=128: wave=64x64 (4x4 MFMA).
// TN=64: wave=64x32 (4x2 MFMA), grid doubles -> 2 blocks/CU for small-N gemm.
template <int TN, bool OUT_F32>
__global__ __launch_bounds__(256) void gemm_bt(const unsigned short* __restrict__ A,
                                               const unsigned short* __restrict__ Bt,
                                               const float* __restrict__ bias,
                                               void* __restrict__ Cp,
                                               int N, int K) {
  __shared__ __attribute__((aligned(16))) unsigned short Atile[128 * 32];
  __shared__ __attribute__((aligned(16))) unsigned short Btile[TN * 32];
  constexpr int NJ = TN / 32;  // 16-col tiles per wave
  const int tid = threadIdx.x;
  const int w = tid >> 6, lane = tid & 63;
  const int quad = lane >> 4, l15 = lane & 15;
  const int m0 = blockIdx.y * 128, n0 = blockIdx.x * TN;
  const int wr = w >> 1, wc = w & 1;
  const int nwc = wc * (TN / 2);
  f32x4 acc[4][NJ] = {};
  for (int kt = 0; kt < K; kt += 32) {
    __syncthreads();  // previous iteration's fragment reads complete
#pragma unroll
    for (int it = 0; it < 2; it++) {      // A: 128 rows
      const int c = it * 256 + tid;       // chunk: row = c>>2, 8-elem k-chunk = c&3
      async_ld16(A + (size_t)(m0 + (c >> 2)) * K + kt + (c & 3) * 8,
                 &Atile[(size_t)(it * 256 + w * 64) * 8]);   // wave-uniform LDS base
    }
#pragma unroll
    for (int it = 0; it < TN / 64; it++) {  // B: TN rows
      const int c = it * 256 + tid;
      async_ld16(Bt + (size_t)(n0 + (c >> 2)) * K + kt + (c & 3) * 8,
                 &Btile[(size_t)(it * 256 + w * 64) * 8]);
    }
    __syncthreads();  // vmcnt(0) drain lands the async copies
    f16x8 af[4], bfr[NJ];
#pragma unroll
    for (int i = 0; i < 4; i++)
      af[i] = *(const f16x8*)&Atile[(wr * 64 + i * 16 + l15) * 32 + quad * 8];
#pragma unroll
    for (int j = 0; j < NJ; j++)
      bfr[j] = *(const f16x8*)&Btile[(nwc + j * 16 + l15) * 32 + quad * 8];
#pragma unroll
    for (int i = 0; i < 4; i++)
#pragma unroll
      for (int j = 0; j < NJ; j++)
        acc[i][j] = MFMA16(af[i], bfr[j], acc[i][j]);
  }
  // epilogue: C/D layout col=lane&15, row=quad*4+reg
#pragma unroll
  for (int j = 0; j < NJ; j++) {
    const int n = n0 + nwc + j * 16 + l15;
    const float bv = bias[n];
#pragma unroll
    for (int i = 0; i < 4; i++) {
      const int mb = m0 + wr * 64 + i * 16 + quad * 4;
#pragma unroll
      for (int r = 0; r < 4; r++) {
        if constexpr (OUT_F32)
          ((float*)Cp)[(size_t)(mb + r) * N + n] = acc[i][j][r] + bv;
        else
          ((unsigned short*)Cp)[(size_t)(mb + r) * N + n] = f2h(acc[i][j][r] + bv);
      }
    }
  }
}

// ---------------- Yat causal flash attention (fp16 in/out, fp32 math) ----------------
// grid: (B*H, 32). Block 256 = 4 waves; wave w owns q rows [16w,16w+16).
// score = dot^2 * rcp(qsq + ksq - 2 dot + 1e-6), causal, online softmax.
// S^T layout: accS = MFMA(K,Q) -> lane owns q = w*16+l15, t = nt*16+quad*4+r.
// P in registers: cvt_pkrtz -> permlane32/16_swap -> PV B-frags.
// Double-buffered Kp/Vt/ksq: 1 barrier/iter. Kp[1] aliases Q staging (frags
// hoisted) and Kp[0] the output transpose. Prefetch distance 2 tiles.
__global__ __launch_bounds__(256, 4) void yat_attn(const unsigned short* __restrict__ qkv,
                                                   unsigned short* __restrict__ outp) {
  __shared__ __attribute__((aligned(16))) unsigned short Kp[2][64 * 72];  // [t][d]; Kp[1]=Q stage
  __shared__ __attribute__((aligned(16))) unsigned short Vt[2][64 * 72];  // [d][t]
  __shared__ float qsq[64], ksq[2][64];
  const int tid = threadIdx.x;
  const int w = tid >> 6, lane = tid & 63;
  const int quad = lane >> 4, l15 = lane & 15;
  const int bh = blockIdx.x, b = bh >> 4, h = bh & 15;
  // dispatch-round-aware qt map: per y-octave per CU; iteration sums uniform.
  const int y = blockIdx.y;
  const int qt = (y < 8) ? 31 - y : (y < 16) ? y - 8 : (y < 24) ? 39 - y : y - 16;
  const unsigned short* base = qkv + (size_t)b * TSEQ * 3072 + h * 64;
  const int t = tid >> 2, dc = (tid & 3) * 16;   // K/Q staging: row t, 16 d's
  const int d0 = tid & 31, tg8 = tid >> 5;       // V staging: 2 d-rows, 8 t's

  // tile-0 K/V loads issued first (latency hides under Q staging)
  uint4 kreg0, kreg1;
  unsigned int vreg[8];
  {
    const unsigned short* gk = base + 1024 + (size_t)t * 3072 + dc;
    kreg0 = *(const uint4*)gk;
    kreg1 = *(const uint4*)(gk + 8);
    const unsigned short* gv = base + 2048 + (size_t)(tg8 * 8) * 3072 + 2 * d0;
#pragma unroll
    for (int s = 0; s < 8; s++)
      vreg[s] = *(const unsigned int*)(gv + (size_t)s * 3072);
  }
  {  // stage Q tile into Kp[1] + row sums of squares (v_dot2_f32_f16)
    const unsigned short* g = base + (size_t)(qt * 64 + t) * 3072 + dc;
    uint4 v0 = *(const uint4*)g;
    uint4 v1 = *(const uint4*)(g + 8);
    *(uint4*)&Kp[1][t * 72 + dc] = v0;
    *(uint4*)&Kp[1][t * 72 + dc + 8] = v1;
    float s = dot2acc(v0.x, 0.f);
    s = dot2acc(v0.y, s); s = dot2acc(v0.z, s); s = dot2acc(v0.w, s);
    s = dot2acc(v1.x, s); s = dot2acc(v1.y, s); s = dot2acc(v1.z, s);
    s = dot2acc(v1.w, s);
    s += __shfl_xor(s, 1);
    s += __shfl_xor(s, 2);
    if ((tid & 3) == 0) qsq[t] = s;
  }
  // commit K [t][d] + ksq + V^T [d][t] from regs into buffer `buf`
  auto commit = [&](int buf) {
    *(uint4*)&Kp[buf][t * 72 + dc] = kreg0;
    *(uint4*)&Kp[buf][t * 72 + dc + 8] = kreg1;
    float s = dot2acc(kreg0.x, 0.f);
    s = dot2acc(kreg0.y, s); s = dot2acc(kreg0.z, s); s = dot2acc(kreg0.w, s);
    s = dot2acc(kreg1.x, s); s = dot2acc(kreg1.y, s); s = dot2acc(kreg1.z, s);
    s = dot2acc(kreg1.w, s);
    s += __shfl_xor(s, 1);
    s += __shfl_xor(s, 2);
    if ((tid & 3) == 0) ksq[buf][t] = s;
    // V^T repack: one v_perm_b32 per output dword (lo-halves / hi-halves)
    uint4 LO, HI;
    LO.x = __builtin_amdgcn_perm(vreg[1], vreg[0], 0x05040100u);
    HI.x = __builtin_amdgcn_perm(vreg[1], vreg[0], 0x07060302u);
    LO.y = __builtin_amdgcn_perm(vreg[3], vreg[2], 0x05040100u);
    HI.y = __builtin_amdgcn_perm(vreg[3], vreg[2], 0x07060302u);
    LO.z = __builtin_amdgcn_perm(vreg[5], vreg[4], 0x05040100u);
    HI.z = __builtin_amdgcn_perm(vreg[5], vreg[4], 0x07060302u);
    LO.w = __builtin_amdgcn_perm(vreg[7], vreg[6], 0x05040100u);
    HI.w = __builtin_amdgcn_perm(vreg[7], vreg[6], 0x07060302u);
    *(uint4*)&Vt[buf][(2 * d0) * 72 + tg8 * 8] = LO;
    *(uint4*)&Vt[buf][(2 * d0 + 1) * 72 + tg8 * 8] = HI;
  };
  commit(0);
  if (qt >= 1) {  // prefetch tile 1
    const unsigned short* gk = base + 1024 + (size_t)(64 + t) * 3072 + dc;
    kreg0 = *(const uint4*)gk;
    kreg1 = *(const uint4*)(gk + 8);
    const unsigned short* gv = base + 2048 + (size_t)(64 + tg8 * 8) * 3072 + 2 * d0;
#pragma unroll
    for (int s = 0; s < 8; s++)
      vreg[s] = *(const unsigned int*)(gv + (size_t)s * 3072);
  }
  __syncthreads();  // Q (Kp[1]) + tile0 (Kp[0]/Vt[0]/ksq[0]) visible
  // hoisted loop-invariant Q fragments (wave w, q rows 16w..16w+16)
  const f16x8 aq0 = *(const f16x8*)&Kp[1][(w * 16 + l15) * 72 + quad * 8];
  const f16x8 aq1 = *(const f16x8*)&Kp[1][(w * 16 + l15) * 72 + 32 + quad * 8];
  const f16x8 onesf = {(_Float16)1.f, (_Float16)1.f, (_Float16)1.f, (_Float16)1.f,
                       (_Float16)1.f, (_Float16)1.f, (_Float16)1.f, (_Float16)1.f};
  const int ql = w * 16 + l15;            // this lane's q row (tile-local)
  const float qsq_eps = qsq[ql] + 1e-6f;  // loop-invariant
  __syncthreads();  // all Q-frag reads done before iter0 commits into Kp[1]

  f32x4 accO[4] = {};                    // O^T: lane q = l15, d = 16i+quad*4+r
  float m_run = 0.f;                     // scores >= 0 so 0 is a valid init max
  float l_acc = 0.f;                     // l in O^T layout: lane q = l15

  for (int kt = 0; kt <= qt; kt++) {
    const int cur = kt & 1;
    // S^T = K Q^T : rows t (quad*4+r per nt), cols q (l15) — critical path first
    f32x4 accS[4] = {};
#pragma unroll
    for (int nt = 0; nt < 4; nt++) {
      const f16x8 bk0 = *(const f16x8*)&Kp[cur][(nt * 16 + l15) * 72 + quad * 8];
      const f16x8 bk1 = *(const f16x8*)&Kp[cur][(nt * 16 + l15) * 72 + 32 + quad * 8];
      accS[nt] = MFMA16(bk0, aq0, accS[nt]);
      accS[nt] = MFMA16(bk1, aq1, accS[nt]);
    }
    // scores: lane q = ql, t = nt*16 + quad*4 + r
    float pv[4][4];
#pragma unroll
    for (int nt = 0; nt < 4; nt++) {
      const f32x4 k4 = *(const f32x4*)&ksq[cur][nt * 16 + quad * 4];
#pragma unroll
      for (int r = 0; r < 4; r++) {
        const float d = accS[nt][r];
        const float den = __builtin_fmaf(-2.f, d, k4[r] + qsq_eps);
        pv[nt][r] = d * d * __builtin_amdgcn_rcpf(den);
      }
    }
    if (kt == qt) {  // causal mask, uniform branch (last iteration only)
#pragma unroll
      for (int nt = 0; nt < 4; nt++)
#pragma unroll
        for (int r = 0; r < 4; r++)
          if (nt * 16 + quad * 4 + r > ql) pv[nt][r] = -1e30f;
    }
    // row max: per-lane tree over 16, then cross-quad (lanes ^16, ^32)
    float tm = fmaxf(fmaxf(fmaxf(pv[0][0], pv[0][1]), fmaxf(pv[0][2], pv[0][3])),
                     fmaxf(fmaxf(pv[1][0], pv[1][1]), fmaxf(pv[1][2], pv[1][3])));
    tm = fmaxf(tm, fmaxf(fmaxf(fmaxf(pv[2][0], pv[2][1]), fmaxf(pv[2][2], pv[2][3])),
                         fmaxf(fmaxf(pv[3][0], pv[3][1]), fmaxf(pv[3][2], pv[3][3]))));
    tm = fmaxf(tm, __shfl_xor(tm, 16));
    tm = fmaxf(tm, __shfl_xor(tm, 32));
    const float mn = fmaxf(m_run, tm);
    const float alpha = __expf(m_run - mn);
    m_run = mn;
    // P = exp(s - m) packed to f16 pairs
    unsigned int pa[4], pb[4];
#pragma unroll
    for (int nt = 0; nt < 4; nt++) {
      pa[nt] = pk_f16(__expf(pv[nt][0] - mn), __expf(pv[nt][1] - mn));
      pb[nt] = pk_f16(__expf(pv[nt][2] - mn), __expf(pv[nt][3] - mn));
    }
    // commit tile kt+1 into the other buffer (vmcnt wait lands here, ~1 iter
    // after load issue); then issue loads for tile kt+2.
    if (kt < qt) commit(cur ^ 1);
    if (kt + 2 <= qt) {
      const unsigned short* gk = base + 1024 + (size_t)((kt + 2) * 64 + t) * 3072 + dc;
      kreg0 = *(const uint4*)gk;
      kreg1 = *(const uint4*)(gk + 8);
      const unsigned short* gv =
          base + 2048 + (size_t)((kt + 2) * 64 + tg8 * 8) * 3072 + 2 * d0;
#pragma unroll
      for (int s = 0; s < 8; s++)
        vreg[s] = *(const unsigned int*)(gv + (size_t)s * 3072);
    }
    // redistribute P into PV B-frags: (w0,w2) = permlane16(permlane32(lo,hi))
    union { f16x8 v; unsigned int u[4]; } bp0, bp1;
    {
      u32x2 s0 = __builtin_amdgcn_permlane32_swap(pa[0], pa[1], false, false);
      u32x2 s1 = __builtin_amdgcn_permlane16_swap(s0.x, s0.y, false, false);
      bp0.u[0] = s1.x; bp0.u[2] = s1.y;
      s0 = __builtin_amdgcn_permlane32_swap(pb[0], pb[1], false, false);
      s1 = __builtin_amdgcn_permlane16_swap(s0.x, s0.y, false, false);
      bp0.u[1] = s1.x; bp0.u[3] = s1.y;
      s0 = __builtin_amdgcn_permlane32_swap(pa[2], pa[3], false, false);
      s1 = __builtin_amdgcn_permlane16_swap(s0.x, s0.y, false, false);
      bp1.u[0] = s1.x; bp1.u[2] = s1.y;
      s0 = __builtin_amdgcn_permlane32_swap(pb[2], pb[3], false, false);
      s1 = __builtin_amdgcn_permlane16_swap(s0.x, s0.y, false, false);
      bp1.u[1] = s1.x; bp1.u[3] = s1.y;
    }
    // rescale O^T (alpha per-lane uniform), l via ones-MFMA, O^T += V^T P^T
#pragma unroll
    for (int i = 0; i < 4; i++) {
      accO[i][0] *= alpha; accO[i][1] *= alpha;
      accO[i][2] *= alpha; accO[i][3] *= alpha;
    }
    f32x4 accL = {};  // D = ones * P^T -> col=l15=q, rows identical = sum_t P[q][t]
    accL = MFMA16(onesf, bp0.v, accL);
    accL = MFMA16(onesf, bp1.v, accL);
#pragma unroll
    for (int i = 0; i < 4; i++) {
      const f16x8 av0 = *(const f16x8*)&Vt[cur][(i * 16 + l15) * 72 + quad * 8];
      const f16x8 av1 = *(const f16x8*)&Vt[cur][(i * 16 + l15) * 72 + 32 + quad * 8];
      accO[i] = MFMA16(av0, bp0.v, accO[i]);
      accO[i] = MFMA16(av1, bp1.v, accO[i]);
    }
    l_acc = l_acc * alpha + accL[0];
    __syncthreads();  // single barrier: reads of cur done; writes of cur^1 done
  }

  // finalize: divide by l (already in O^T lane layout), transpose via Kp[0], store
  // (loop's final barrier already ordered all waves' last reads)
  const float linv = 1.0f / l_acc;
#pragma unroll
  for (int i = 0; i < 4; i++)
#pragma unroll
    for (int r = 0; r < 4; r++)
      Kp[0][(w * 16 + l15) * 72 + i * 16 + quad * 4 + r] = f2h(accO[i][r] * linv);
  __syncthreads();
  {
    uint4 o0 = *(const uint4*)&Kp[0][t * 72 + dc];
    uint4 o1 = *(const uint4*)&Kp[0][t * 72 + dc + 8];
    unsigned short* g = outp + (size_t)(b * TSEQ + qt * 64 + t) * 1024 + h * 64 + dc;
    *(uint4*)g = o0;
    *(uint4*)(g + 8) = o1;
  }
}

extern "C" void kernel_launch(void* const* d_in, const int* in_sizes, int n_in,
                              void* d_out, int out_size, void* d_ws, size_t ws_size,
                              hipStream_t stream) {
  (void)in_sizes; (void)n_in; (void)out_size; (void)ws_size;
  const float* x     = (const float*)d_in[0];  // [2,2048,1024] fp32
  const float* w_qkv = (const float*)d_in[1];  // [1024,3072]   fp32
  const float* b_qkv = (const float*)d_in[2];  // [3072]        fp32
  const float* w_out = (const float*)d_in[3];  // [1024,1024]   fp32
  const float* b_out = (const float*)d_in[4];  // [1024]        fp32
  float* out = (float*)d_out;                  // [2,2048,1024] fp32

  unsigned short* wqkvT  = (unsigned short*)d_ws;                    // [3072][1024] fp16
  unsigned short* woT    = wqkvT + (size_t)3072 * 1024;              // [1024][1024] fp16
  unsigned short* qkvws  = woT + (size_t)1024 * 1024;                // [4096][3072] fp16
  unsigned short* xh     = qkvws + (size_t)4096 * 3072;              // [4096][1024] fp16
  unsigned short* attnws = xh;  // alias: xh dead after gemm1, attnws born at yat_attn

  prep<<<dim3(6144), 256, 0, stream>>>(x, xh, w_qkv, wqkvT, w_out, woT);
  gemm_bt<128, false><<<dim3(3072 / 128, 4096 / 128), 256, 0, stream>>>(xh, wqkvT, b_qkv, qkvws, 3072, 1024);
  yat_attn<<<dim3(BATCH * 16, 32), 256, 0, stream>>>(qkvws, attnws);
  gemm_bt<64, true><<<dim3(1024 / 64, 4096 / 128), 256, 0, stream>>>(attnws, woT, b_out, out, 1024, 1024);
}